// Round 3
// baseline (655.068 us; speedup 1.0000x reference)
//
#include <hip/hip_runtime.h>
#include <cstdint>
#include <cstddef>

#define D_ 1024
#define S_ 2048
#define B_ 32

typedef float f32x4 __attribute__((ext_vector_type(4)));
typedef __bf16 v8bf __attribute__((ext_vector_type(8)));

__device__ __forceinline__ unsigned short f2bf_rne(float f) {
  unsigned int u = __float_as_uint(f);
  u = (u + 0x7FFFu + ((u >> 16) & 1u)) >> 16;
  return (unsigned short)u;
}

// pack two fp32 into packed bf16x2 (round-half-up) via byte-perm
__device__ __forceinline__ unsigned int bfpack(float f0, float f1) {
  unsigned int u0 = __float_as_uint(f0) + 0x8000u;
  unsigned int u1 = __float_as_uint(f1) + 0x8000u;
  return __builtin_amdgcn_perm(u1, u0, 0x07060302u);  // lo=hi16(u0), hi=hi16(u1)
}

__device__ __forceinline__ float tanh_fast(float x) {
  float ax = __builtin_fabsf(x);
  float e = __expf(2.0f * ax);
  float r = 1.0f - 2.0f * __builtin_amdgcn_rcpf(e + 1.0f);
  return __builtin_copysignf(r, x);
}

// ---------------- K0: fused prep ----------------
// blocks [0,1024): W_c fp32 -> bf16 ; blocks [1024,2048): tadd = x@W_in.T + b_c
__global__ void k_prep(const float* __restrict__ wc, unsigned short* __restrict__ wcb,
                       const float* __restrict__ x, const float* __restrict__ win,
                       const float* __restrict__ bc, float* __restrict__ tadd) {
  __shared__ float wl[D_];
  int t = threadIdx.x;
  if (blockIdx.x < 1024) {
    int e = blockIdx.x;
    float4 v = ((const float4*)(wc + (size_t)e * D_))[t];
    ushort4 o;
    o.x = f2bf_rne(v.x); o.y = f2bf_rne(v.y); o.z = f2bf_rne(v.z); o.w = f2bf_rne(v.w);
    ((ushort4*)(wcb + (size_t)e * D_))[t] = o;
    return;
  }
  int e = blockIdx.x - 1024;
  ((float4*)wl)[t] = ((const float4*)(win + (size_t)e * D_))[t];
  __syncthreads();
  int w = t >> 6, lane = t & 63;
  float bce = bc[e];
  for (int bb = w; bb < B_; bb += 4) {
    const float* xr = x + (size_t)bb * D_ + lane * 16;
    const float* wr = wl + lane * 16;
    float p = 0.f;
#pragma unroll
    for (int c = 0; c < 4; ++c) {
      float4 xv = ((const float4*)xr)[c];
      float4 wv = ((const float4*)wr)[c];
      p += xv.x * wv.x + xv.y * wv.y + xv.z * wv.z + xv.w * wv.w;
    }
#pragma unroll
    for (int off = 32; off; off >>= 1) p += __shfl_xor(p, off, 64);
    if (lane == 0) tadd[(size_t)bb * D_ + e] = p + bce;
  }
}

// ---------------- K2: fused scores GEMM, pipelined K-loop ----------------
// Double-buffered LDS, ONE barrier per kt. A(kt+1) global->regs issued at top of
// compute(kt) (latency hidden behind MFMA), converted+written to As[nxt] after MFMA.
// B(kt+1) DMA'd to Bs[nxt] during compute(kt). part[pslice][b][s], pslice=et*2+e_half.
__global__ __launch_bounds__(256, 2) void k_scores(
    const float* __restrict__ ctx, const unsigned short* __restrict__ wcb,
    const float* __restrict__ tadd, const float* __restrict__ wv,
    float* __restrict__ part) {
  __shared__ unsigned short As[2][128 * 32];
  __shared__ unsigned short Bs[2][128 * 32];
  int g = blockIdx.x;
  int xcd = g & 7;
  int j = g >> 3;
  int stile = xcd * 64 + (j >> 3);   // XCD-grouped: 8 e-tiles of one s-tile per XCD
  int et = j & 7;
  int b = stile >> 4;
  int s0 = (stile & 15) << 7;
  int e0 = et << 7;
  int t = threadIdx.x;
  int w = t >> 6, lane = t & 63;

  f32x4 acc[4][4];
#pragma unroll
  for (int i = 0; i < 4; ++i)
#pragma unroll
    for (int jj = 0; jj < 4; ++jj) acc[i][jj] = (f32x4){0.f, 0.f, 0.f, 0.f};

  const int m = lane & 15, q = lane >> 4;
  const int ws_ = (w & 1) << 6, we_ = (w >> 1) << 6;

  const int brow = lane >> 2;        // B DMA: 16 rows per issue
  const int bcol = (lane & 3) << 3;  // 8 bf16 = 16B per lane
  const int arow = t >> 1;           // A: 2 threads per row, 16 fp32 each
  const int acol = (t & 1) << 4;

  const size_t ctx_base = ((size_t)b * S_ + s0) * D_;
  const size_t wc_base = (size_t)e0 * D_;
  const float* actx = ctx + ctx_base + (size_t)arow * D_ + acol;

  float4 av0, av1, av2, av3;

  // ---- prologue: stage tile 0 ----
  {
    const float* gp = actx;
    av0 = ((const float4*)gp)[0]; av1 = ((const float4*)gp)[1];
    av2 = ((const float4*)gp)[2]; av3 = ((const float4*)gp)[3];
#pragma unroll
    for (int p = 0; p < 2; ++p) {
      int row = (w << 5) + (p << 4) + brow;
      const unsigned short* gb = wcb + wc_base + (size_t)row * D_ + bcol;
      unsigned short* lp = Bs[0] + (((w << 5) + (p << 4)) << 5);
      __builtin_amdgcn_global_load_lds(
          (const __attribute__((address_space(1))) unsigned int*)gb,
          (__attribute__((address_space(3))) unsigned int*)lp, 16, 0, 0);
    }
    uint4 o0, o1;
    o0.x = bfpack(av0.x, av0.y); o0.y = bfpack(av0.z, av0.w);
    o0.z = bfpack(av1.x, av1.y); o0.w = bfpack(av1.z, av1.w);
    o1.x = bfpack(av2.x, av2.y); o1.y = bfpack(av2.z, av2.w);
    o1.z = bfpack(av3.x, av3.y); o1.w = bfpack(av3.z, av3.w);
    *(uint4*)(As[0] + t * 16) = o0;
    *(uint4*)(As[0] + t * 16 + 8) = o1;
  }

  for (int kt = 0; kt < 32; ++kt) {
    const int cur = kt & 1, nxt = cur ^ 1;
    __syncthreads();  // As[cur]/Bs[cur] ready; prev iter's reads of [nxt] done
    // prefetch issues for kt+1 (latency hidden behind MFMA phase)
    if (kt < 31) {
      const int k0n = (kt + 1) << 5;
      const float* gp = actx + k0n;
      av0 = ((const float4*)gp)[0]; av1 = ((const float4*)gp)[1];
      av2 = ((const float4*)gp)[2]; av3 = ((const float4*)gp)[3];
#pragma unroll
      for (int p = 0; p < 2; ++p) {
        int row = (w << 5) + (p << 4) + brow;
        const unsigned short* gb = wcb + wc_base + (size_t)row * D_ + k0n + bcol;
        unsigned short* lp = Bs[nxt] + (((w << 5) + (p << 4)) << 5);
        __builtin_amdgcn_global_load_lds(
            (const __attribute__((address_space(1))) unsigned int*)gb,
            (__attribute__((address_space(3))) unsigned int*)lp, 16, 0, 0);
      }
    }
    // compute tile kt
    v8bf a[4], bf[4];
#pragma unroll
    for (int i = 0; i < 4; ++i)
      a[i] = *(const v8bf*)(As[cur] + ((ws_ + (i << 4) + m) << 5) + (q << 3));
#pragma unroll
    for (int jj = 0; jj < 4; ++jj)
      bf[jj] = *(const v8bf*)(Bs[cur] + ((we_ + (jj << 4) + m) << 5) + (q << 3));
#pragma unroll
    for (int i = 0; i < 4; ++i)
#pragma unroll
      for (int jj = 0; jj < 4; ++jj)
        acc[i][jj] = __builtin_amdgcn_mfma_f32_16x16x32_bf16(a[i], bf[jj], acc[i][jj], 0, 0, 0);
    // convert + stage A(kt+1) into As[nxt] (waits its vmcnt here, post-MFMA)
    if (kt < 31) {
      uint4 o0, o1;
      o0.x = bfpack(av0.x, av0.y); o0.y = bfpack(av0.z, av0.w);
      o0.z = bfpack(av1.x, av1.y); o0.w = bfpack(av1.z, av1.w);
      o1.x = bfpack(av2.x, av2.y); o1.y = bfpack(av2.z, av2.w);
      o1.z = bfpack(av3.x, av3.y); o1.w = bfpack(av3.z, av3.w);
      *(uint4*)(As[nxt] + t * 16) = o0;
      *(uint4*)(As[nxt] + t * 16 + 8) = o1;
    }
  }

  // epilogue: tanh(acc + tadd[b,e]) * w_v[e], reduce over e within wave
  float sp[4][4];
#pragma unroll
  for (int i = 0; i < 4; ++i)
#pragma unroll
    for (int r = 0; r < 4; ++r) sp[i][r] = 0.f;
#pragma unroll
  for (int jj = 0; jj < 4; ++jj) {
    int e = e0 + we_ + (jj << 4) + m;
    float ta = tadd[(size_t)b * D_ + e];
    float wve = wv[e];
#pragma unroll
    for (int i = 0; i < 4; ++i)
#pragma unroll
      for (int r = 0; r < 4; ++r)
        sp[i][r] += tanh_fast(acc[i][jj][r] + ta) * wve;
  }
#pragma unroll
  for (int off = 1; off < 16; off <<= 1)
#pragma unroll
    for (int i = 0; i < 4; ++i)
#pragma unroll
      for (int r = 0; r < 4; ++r) sp[i][r] += __shfl_xor(sp[i][r], off, 64);
  if (m == 0) {
    int ps = (et << 1) + (w >> 1);
    float* dst = part + ((size_t)ps * B_ + b) * S_ + s0 + ws_ + (q << 2);
#pragma unroll
    for (int i = 0; i < 4; ++i)
#pragma unroll
      for (int r = 0; r < 4; ++r) dst[(i << 4) + r] = sp[i][r];
  }
}

// ---------------- K3: sum 16 partial slices, softmax over S, write attn_w ----------------
__global__ void k_softmax(const float* __restrict__ part, float* __restrict__ attn) {
  __shared__ float red[4];
  int b = blockIdx.x, t = threadIdx.x;
  int w = t >> 6, lane = t & 63;
  float sc[8];
#pragma unroll
  for (int u = 0; u < 8; ++u) {
    int s = t + (u << 8);
    float v = 0.f;
#pragma unroll
    for (int p = 0; p < 16; ++p) v += part[((size_t)p * B_ + b) * S_ + s];
    sc[u] = v;
  }
  float mx = sc[0];
#pragma unroll
  for (int u = 1; u < 8; ++u) mx = fmaxf(mx, sc[u]);
#pragma unroll
  for (int off = 32; off; off >>= 1) mx = fmaxf(mx, __shfl_xor(mx, off, 64));
  if (lane == 0) red[w] = mx;
  __syncthreads();
  mx = fmaxf(fmaxf(red[0], red[1]), fmaxf(red[2], red[3]));
  float sum = 0.f;
#pragma unroll
  for (int u = 0; u < 8; ++u) { sc[u] = __expf(sc[u] - mx); sum += sc[u]; }
#pragma unroll
  for (int off = 32; off; off >>= 1) sum += __shfl_xor(sum, off, 64);
  __syncthreads();
  if (lane == 0) red[w] = sum;
  __syncthreads();
  sum = red[0] + red[1] + red[2] + red[3];
  float rv = 1.0f / sum;
#pragma unroll
  for (int u = 0; u < 8; ++u) attn[(size_t)b * S_ + t + (u << 8)] = sc[u] * rv;
}

// ---------------- K4: partial weighted sums, full-row coalesced ----------------
__global__ void k_weighted(const float* __restrict__ ctx, const float* __restrict__ attn,
                           float* __restrict__ pw) {
  __shared__ float al[128];
  int bid = blockIdx.x;
  int b = bid >> 4, c = bid & 15;
  int t = threadIdx.x;
  int s0 = c << 7;
  if (t < 128) al[t] = attn[(size_t)b * S_ + s0 + t];
  __syncthreads();
  f32x4 acc = {0.f, 0.f, 0.f, 0.f};
  const float* base = ctx + ((size_t)b * S_ + s0) * D_ + (t << 2);
#pragma unroll 4
  for (int s = 0; s < 128; ++s) {
    float wgt = al[s];
    float4 v = *(const float4*)(base + (size_t)s * D_);
    acc.x += wgt * v.x; acc.y += wgt * v.y; acc.z += wgt * v.z; acc.w += wgt * v.w;
  }
  *(f32x4*)(pw + ((size_t)(c * B_ + b)) * D_ + (t << 2)) = acc;
}

// ---------------- K4b: reduce the 16 chunk partials ----------------
__global__ void k_wred(const float* __restrict__ pw, float* __restrict__ wgt) {
  int b = blockIdx.x, t = threadIdx.x;
  f32x4 v = {0.f, 0.f, 0.f, 0.f};
#pragma unroll
  for (int c = 0; c < 16; ++c) {
    f32x4 u = *(const f32x4*)(pw + ((size_t)(c * B_ + b)) * D_ + (t << 2));
    v.x += u.x; v.y += u.y; v.z += u.z; v.w += u.w;
  }
  *(f32x4*)(wgt + (size_t)b * D_ + (t << 2)) = v;
}

// ---------------- K5: h[b,j] = tanh( [weighted|x][b,:] . W_out[j,:] ) ----------------
__global__ void k_out(const float* __restrict__ wgt, const float* __restrict__ x,
                      const float* __restrict__ wo, float* __restrict__ out) {
  __shared__ float wl[2 * D_];
  int jrow = blockIdx.x, t = threadIdx.x;
#pragma unroll
  for (int u = 0; u < 2; ++u)
    ((float4*)wl)[t + (u << 8)] = ((const float4*)(wo + (size_t)jrow * 2 * D_))[t + (u << 8)];
  __syncthreads();
  int w = t >> 6, lane = t & 63;
  for (int bb = w; bb < B_; bb += 4) {
    const float* src = (lane < 32) ? (wgt + (size_t)bb * D_ + (lane << 5))
                                   : (x + (size_t)bb * D_ + ((lane - 32) << 5));
    const float* wr = wl + (lane << 5);
    float p = 0.f;
#pragma unroll
    for (int c = 0; c < 8; ++c) {
      float4 a = ((const float4*)src)[c];
      float4 ww = ((const float4*)wr)[c];
      p += a.x * ww.x + a.y * ww.y + a.z * ww.z + a.w * ww.w;
    }
#pragma unroll
    for (int off = 32; off; off >>= 1) p += __shfl_xor(p, off, 64);
    if (lane == 0) out[(size_t)bb * D_ + jrow] = tanh_fast(p);
  }
}

extern "C" void kernel_launch(void* const* d_in, const int* in_sizes, int n_in,
                              void* d_out, int out_size, void* d_ws, size_t ws_size,
                              hipStream_t stream) {
  const float* x   = (const float*)d_in[0];
  const float* ctx = (const float*)d_in[1];
  const float* win = (const float*)d_in[2];
  const float* wc  = (const float*)d_in[3];
  const float* bc  = (const float*)d_in[4];
  const float* wv  = (const float*)d_in[5];
  const float* wo  = (const float*)d_in[6];
  float* out = (float*)d_out;  // [0,32768): h_tilde, [32768,98304): attn_w

  char* ws = (char*)d_ws;
  float* tadd = (float*)ws;                                          // 128 KiB
  float* part = (float*)(ws + 131072);                               // 4 MiB
  float* pw   = part;                                                // aliases part (dead after softmax)
  float* wgt  = (float*)(ws + 131072 + 4194304);                     // 128 KiB
  unsigned short* wcb = (unsigned short*)(ws + 131072 + 4194304 + 131072);  // 2 MiB

  k_prep    <<<2048, 256, 0, stream>>>(wc, wcb, x, win, bc, tadd);
  k_scores  <<<4096, 256, 0, stream>>>(ctx, wcb, tadd, wv, part);
  k_softmax <<<32,   256, 0, stream>>>(part, out + 32768);
  k_weighted<<<512,  256, 0, stream>>>(ctx, out + 32768, pw);
  k_wred    <<<32,   256, 0, stream>>>(pw, wgt);
  k_out     <<<1024, 256, 0, stream>>>(wgt, x, wo, out);
}

// Round 4
// 611.156 us; speedup vs baseline: 1.0719x; 1.0719x over previous
//
#include <hip/hip_runtime.h>
#include <cstdint>
#include <cstddef>

#define D_ 1024
#define S_ 2048
#define B_ 32

typedef float f32x4 __attribute__((ext_vector_type(4)));
typedef __bf16 v8bf __attribute__((ext_vector_type(8)));

__device__ __forceinline__ unsigned short f2bf_rne(float f) {
  unsigned int u = __float_as_uint(f);
  u = (u + 0x7FFFu + ((u >> 16) & 1u)) >> 16;
  return (unsigned short)u;
}

// pack two fp32 into packed bf16x2 (round-half-up) via byte-perm
__device__ __forceinline__ unsigned int bfpack(float f0, float f1) {
  unsigned int u0 = __float_as_uint(f0) + 0x8000u;
  unsigned int u1 = __float_as_uint(f1) + 0x8000u;
  return __builtin_amdgcn_perm(u1, u0, 0x07060302u);  // lo=hi16(u0), hi=hi16(u1)
}

__device__ __forceinline__ float tanh_fast(float x) {
  float ax = __builtin_fabsf(x);
  float e = __expf(2.0f * ax);
  float r = 1.0f - 2.0f * __builtin_amdgcn_rcpf(e + 1.0f);
  return __builtin_copysignf(r, x);
}

// ---------------- K0: fused prep ----------------
// blocks [0,1024): W_c fp32 -> bf16 ; blocks [1024,2048): tadd = x@W_in.T + b_c
__global__ void k_prep(const float* __restrict__ wc, unsigned short* __restrict__ wcb,
                       const float* __restrict__ x, const float* __restrict__ win,
                       const float* __restrict__ bc, float* __restrict__ tadd) {
  __shared__ float wl[D_];
  int t = threadIdx.x;
  if (blockIdx.x < 1024) {
    int e = blockIdx.x;
    float4 v = ((const float4*)(wc + (size_t)e * D_))[t];
    ushort4 o;
    o.x = f2bf_rne(v.x); o.y = f2bf_rne(v.y); o.z = f2bf_rne(v.z); o.w = f2bf_rne(v.w);
    ((ushort4*)(wcb + (size_t)e * D_))[t] = o;
    return;
  }
  int e = blockIdx.x - 1024;
  ((float4*)wl)[t] = ((const float4*)(win + (size_t)e * D_))[t];
  __syncthreads();
  int w = t >> 6, lane = t & 63;
  float bce = bc[e];
  for (int bb = w; bb < B_; bb += 4) {
    const float* xr = x + (size_t)bb * D_ + lane * 16;
    const float* wr = wl + lane * 16;
    float p = 0.f;
#pragma unroll
    for (int c = 0; c < 4; ++c) {
      float4 xv = ((const float4*)xr)[c];
      float4 wv = ((const float4*)wr)[c];
      p += xv.x * wv.x + xv.y * wv.y + xv.z * wv.z + xv.w * wv.w;
    }
#pragma unroll
    for (int off = 32; off; off >>= 1) p += __shfl_xor(p, off, 64);
    if (lane == 0) tadd[(size_t)bb * D_ + e] = p + bce;
  }
}

// ---------------- K2: fused scores GEMM, 128s x 256e block, wave tile 64x128 ----------------
// m97-style single-buffer, 2 barriers per kt. part[pslice][b][s], pslice = et*2 + e_half (8).
__global__ __launch_bounds__(256, 2) void k_scores(
    const float* __restrict__ ctx, const unsigned short* __restrict__ wcb,
    const float* __restrict__ tadd, const float* __restrict__ wv,
    float* __restrict__ part) {
  __shared__ unsigned short As[128 * 32];   // 8 KB
  __shared__ unsigned short Bs[256 * 32];   // 16 KB
  int g = blockIdx.x;                       // 2048 blocks
  int xcd = g & 7;
  int j = g >> 3;                           // [0,256)
  int stile = xcd * 64 + (j >> 2);          // 4 et-blocks of one stile per XCD
  int et = j & 3;
  int b = stile >> 4;
  int s0 = (stile & 15) << 7;
  int e0 = et << 8;
  int t = threadIdx.x;
  int w = t >> 6, lane = t & 63;

  f32x4 acc[4][8];
#pragma unroll
  for (int i = 0; i < 4; ++i)
#pragma unroll
    for (int jj = 0; jj < 8; ++jj) acc[i][jj] = (f32x4){0.f, 0.f, 0.f, 0.f};

  const int m = lane & 15, q = lane >> 4;
  const int ws_ = (w & 1) << 6;        // s-offset of wave: 0 or 64
  const int we_ = (w >> 1) << 7;       // e-offset of wave: 0 or 128

  const int brow = lane >> 2;          // B DMA: 16 rows per issue
  const int bcol = (lane & 3) << 3;    // 8 bf16 = 16B per lane
  const int arow = t >> 2;             // A: 4 thr/row, 64 rows per pass, 2 passes
  const int acol = (t & 3) << 3;       // 8 fp32 per thread -> 16B bf16 write

  const size_t ctx_base = ((size_t)b * S_ + s0) * D_;
  const size_t wc_base = (size_t)e0 * D_;

  for (int kt = 0; kt < 32; ++kt) {
    const int k0 = kt << 5;
    __syncthreads();
    // B tile: 256 rows via DMA, wave w covers rows [w*64, w*64+64)
#pragma unroll
    for (int p = 0; p < 4; ++p) {
      int row = (w << 6) + (p << 4) + brow;
      const unsigned short* gb = wcb + wc_base + (size_t)row * D_ + k0 + bcol;
      unsigned short* lp = Bs + (((w << 6) + (p << 4)) << 5);
      __builtin_amdgcn_global_load_lds(
          (const __attribute__((address_space(1))) unsigned int*)gb,
          (__attribute__((address_space(3))) unsigned int*)lp, 16, 0, 0);
    }
    // A tile: 128 rows x 32 k fp32 -> bf16, conflict-clean 16B writes
#pragma unroll
    for (int p = 0; p < 2; ++p) {
      int row = (p << 6) + arow;
      const float* gp = ctx + ctx_base + (size_t)row * D_ + k0 + acol;
      float4 v0 = ((const float4*)gp)[0];
      float4 v1 = ((const float4*)gp)[1];
      uint4 o;
      o.x = bfpack(v0.x, v0.y); o.y = bfpack(v0.z, v0.w);
      o.z = bfpack(v1.x, v1.y); o.w = bfpack(v1.z, v1.w);
      *(uint4*)(As + (row << 5) + acol) = o;
    }
    __syncthreads();
    v8bf a[4], bf[8];
#pragma unroll
    for (int i = 0; i < 4; ++i)
      a[i] = *(const v8bf*)(As + ((ws_ + (i << 4) + m) << 5) + (q << 3));
#pragma unroll
    for (int jj = 0; jj < 8; ++jj)
      bf[jj] = *(const v8bf*)(Bs + ((we_ + (jj << 4) + m) << 5) + (q << 3));
#pragma unroll
    for (int i = 0; i < 4; ++i)
#pragma unroll
      for (int jj = 0; jj < 8; ++jj)
        acc[i][jj] = __builtin_amdgcn_mfma_f32_16x16x32_bf16(a[i], bf[jj], acc[i][jj], 0, 0, 0);
  }

  // epilogue: tanh(acc + tadd[b,e]) * w_v[e], reduce over the wave's 128 e-cols
  float sp[4][4];
#pragma unroll
  for (int i = 0; i < 4; ++i)
#pragma unroll
    for (int r = 0; r < 4; ++r) sp[i][r] = 0.f;
#pragma unroll
  for (int jj = 0; jj < 8; ++jj) {
    int e = e0 + we_ + (jj << 4) + m;
    float ta = tadd[(size_t)b * D_ + e];
    float wve = wv[e];
#pragma unroll
    for (int i = 0; i < 4; ++i)
#pragma unroll
      for (int r = 0; r < 4; ++r)
        sp[i][r] += tanh_fast(acc[i][jj][r] + ta) * wve;
  }
#pragma unroll
  for (int off = 1; off < 16; off <<= 1)
#pragma unroll
    for (int i = 0; i < 4; ++i)
#pragma unroll
      for (int r = 0; r < 4; ++r) sp[i][r] += __shfl_xor(sp[i][r], off, 64);
  if (m == 0) {
    int ps = (et << 1) + (w >> 1);
    float* dst = part + ((size_t)ps * B_ + b) * S_ + s0 + ws_ + (q << 2);
#pragma unroll
    for (int i = 0; i < 4; ++i)
#pragma unroll
      for (int r = 0; r < 4; ++r) dst[(i << 4) + r] = sp[i][r];
  }
}

// ---------------- K3: sum 8 partial slices, softmax over S, write attn_w ----------------
__global__ void k_softmax(const float* __restrict__ part, float* __restrict__ attn) {
  __shared__ float red[4];
  int b = blockIdx.x, t = threadIdx.x;
  int w = t >> 6, lane = t & 63;
  float sc[8];
#pragma unroll
  for (int u = 0; u < 8; ++u) {
    int s = t + (u << 8);
    float v = 0.f;
#pragma unroll
    for (int p = 0; p < 8; ++p) v += part[((size_t)p * B_ + b) * S_ + s];
    sc[u] = v;
  }
  float mx = sc[0];
#pragma unroll
  for (int u = 1; u < 8; ++u) mx = fmaxf(mx, sc[u]);
#pragma unroll
  for (int off = 32; off; off >>= 1) mx = fmaxf(mx, __shfl_xor(mx, off, 64));
  if (lane == 0) red[w] = mx;
  __syncthreads();
  mx = fmaxf(fmaxf(red[0], red[1]), fmaxf(red[2], red[3]));
  float sum = 0.f;
#pragma unroll
  for (int u = 0; u < 8; ++u) { sc[u] = __expf(sc[u] - mx); sum += sc[u]; }
#pragma unroll
  for (int off = 32; off; off >>= 1) sum += __shfl_xor(sum, off, 64);
  __syncthreads();
  if (lane == 0) red[w] = sum;
  __syncthreads();
  sum = red[0] + red[1] + red[2] + red[3];
  float rv = 1.0f / sum;
#pragma unroll
  for (int u = 0; u < 8; ++u) attn[(size_t)b * S_ + t + (u << 8)] = sc[u] * rv;
}

// ---------------- K4: partial weighted sums, 64-row chunks, full-row coalesced ----------------
// grid = 32 b x 32 chunks; pw[chunk][b][d]
__global__ void k_weighted(const float* __restrict__ ctx, const float* __restrict__ attn,
                           float* __restrict__ pw) {
  __shared__ float al[64];
  int bid = blockIdx.x;
  int b = bid >> 5, c = bid & 31;
  int t = threadIdx.x;
  int s0 = c << 6;
  if (t < 64) al[t] = attn[(size_t)b * S_ + s0 + t];
  __syncthreads();
  f32x4 acc = {0.f, 0.f, 0.f, 0.f};
  const float* base = ctx + ((size_t)b * S_ + s0) * D_ + (t << 2);
#pragma unroll 8
  for (int s = 0; s < 64; ++s) {
    float wgt = al[s];
    float4 v = *(const float4*)(base + (size_t)s * D_);
    acc.x += wgt * v.x; acc.y += wgt * v.y; acc.z += wgt * v.z; acc.w += wgt * v.w;
  }
  *(f32x4*)(pw + ((size_t)(c * B_ + b)) * D_ + (t << 2)) = acc;
}

// ---------------- K4b: reduce the 32 chunk partials ----------------
__global__ void k_wred(const float* __restrict__ pw, float* __restrict__ wgt) {
  int b = blockIdx.x, t = threadIdx.x;
  f32x4 v = {0.f, 0.f, 0.f, 0.f};
#pragma unroll
  for (int c = 0; c < 32; ++c) {
    f32x4 u = *(const f32x4*)(pw + ((size_t)(c * B_ + b)) * D_ + (t << 2));
    v.x += u.x; v.y += u.y; v.z += u.z; v.w += u.w;
  }
  *(f32x4*)(wgt + (size_t)b * D_ + (t << 2)) = v;
}

// ---------------- K5: h[b,j] = tanh( [weighted|x][b,:] . W_out[j,:] ) ----------------
__global__ void k_out(const float* __restrict__ wgt, const float* __restrict__ x,
                      const float* __restrict__ wo, float* __restrict__ out) {
  __shared__ float wl[2 * D_];
  int jrow = blockIdx.x, t = threadIdx.x;
#pragma unroll
  for (int u = 0; u < 2; ++u)
    ((float4*)wl)[t + (u << 8)] = ((const float4*)(wo + (size_t)jrow * 2 * D_))[t + (u << 8)];
  __syncthreads();
  int w = t >> 6, lane = t & 63;
  for (int bb = w; bb < B_; bb += 4) {
    const float* src = (lane < 32) ? (wgt + (size_t)bb * D_ + (lane << 5))
                                   : (x + (size_t)bb * D_ + ((lane - 32) << 5));
    const float* wr = wl + (lane << 5);
    float p = 0.f;
#pragma unroll
    for (int c = 0; c < 8; ++c) {
      float4 a = ((const float4*)src)[c];
      float4 ww = ((const float4*)wr)[c];
      p += a.x * ww.x + a.y * ww.y + a.z * ww.z + a.w * ww.w;
    }
#pragma unroll
    for (int off = 32; off; off >>= 1) p += __shfl_xor(p, off, 64);
    if (lane == 0) out[(size_t)bb * D_ + jrow] = tanh_fast(p);
  }
}

extern "C" void kernel_launch(void* const* d_in, const int* in_sizes, int n_in,
                              void* d_out, int out_size, void* d_ws, size_t ws_size,
                              hipStream_t stream) {
  const float* x   = (const float*)d_in[0];
  const float* ctx = (const float*)d_in[1];
  const float* win = (const float*)d_in[2];
  const float* wc  = (const float*)d_in[3];
  const float* bc  = (const float*)d_in[4];
  const float* wv  = (const float*)d_in[5];
  const float* wo  = (const float*)d_in[6];
  float* out = (float*)d_out;  // [0,32768): h_tilde, [32768,98304): attn_w

  char* ws = (char*)d_ws;
  float* tadd = (float*)ws;                              // 128 KiB
  float* pw   = (float*)(ws + 131072);                   // 4 MiB (first 2 MiB doubles as part)
  float* part = pw;                                      // 8 x 32 x 2048 x 4B = 2 MiB
  float* wgt  = (float*)(ws + 131072 + 4194304);         // 128 KiB
  unsigned short* wcb = (unsigned short*)(ws + 131072 + 4194304 + 131072);  // 2 MiB

  k_prep    <<<2048, 256, 0, stream>>>(wc, wcb, x, win, bc, tadd);
  k_scores  <<<2048, 256, 0, stream>>>(ctx, wcb, tadd, wv, part);
  k_softmax <<<32,   256, 0, stream>>>(part, out + 32768);
  k_weighted<<<1024, 256, 0, stream>>>(ctx, out + 32768, pw);
  k_wred    <<<32,   256, 0, stream>>>(pw, wgt);
  k_out     <<<1024, 256, 0, stream>>>(wgt, x, wo, out);
}